// Round 9
// baseline (104.122 us; speedup 1.0000x reference)
//
#include <hip/hip_runtime.h>

#define HH 479
#define WW 639
#define BATCH 8
#define NBLK (20 * 30 * 8)   // 4800 blocks

// Tile: 32 cols x 16 rows per block, 256 threads, 2 px/thread (cols 2tx, 2tx+1).
// Separable moments per (output-row i, window-col c):
//   S1=SUM d^2, Sb=SUM b d^2, Sbb=SUM b^2 d^2, T1=SUM d, Tb=SUM b d  (8 rows)
// Adjacent pixels share 7/8 window columns with ABSOLUTE weights {1,a_c,a_c^2}
// -> 9 shared core sums over 7 records + 1 unique tap per pixel.
//
// Solve (f32, R5-validated): A_hat = M + eps I - s s^T/64 is PD; Sherman-
// Morrison => (M+eps I)^-1 s = A_hat^-1 s * positive scalar -> identical unit
// normal; centered A_hat kills the ~1e8 raw-moment cofactor cancellation.
//
// Retirement (R9): each block STORES its partial into acc[block_id] (every
// slot written every launch -> no memset dispatch needed); finalize kernel
// sums 4800 doubles. (R2/R3: fence+counter readback serializes retirement,
// +130 us. R4: atomics needed memset; stores don't.)

__device__ __forceinline__ void solve_normal(
    float xx, float xy, float xz, float yy, float yz, float zz,
    float xs, float ys, float zs,
    float a_c, float b_c, float d0,
    float* nx, float* ny, float* nz)
{
    const float EPSV = 1e-6f;
    const float inv64 = 1.0f / 64.0f;
    float hx = xs * inv64, hy = ys * inv64, hz = zs * inv64;
    float cxx = fmaf(-hx, xs, xx) + EPSV;
    float cxy = fmaf(-hx, ys, xy);
    float cxz = fmaf(-hx, zs, xz);
    float cyy = fmaf(-hy, ys, yy) + EPSV;
    float cyz = fmaf(-hy, zs, yz);
    float czz = fmaf(-hz, zs, zz) + EPSV;
    float c00 = fmaf(cyy, czz, -cyz * cyz);
    float c01 = fmaf(cxz, cyz, -cxy * czz);
    float c02 = fmaf(cxy, cyz, -cxz * cyy);
    float c11 = fmaf(cxx, czz, -cxz * cxz);
    float c12 = fmaf(cxy, cxz, -cxx * cyz);
    float c22 = fmaf(cxx, cyy, -cxy * cxy);
    float m0 = fmaf(c00, xs, fmaf(c01, ys, c02 * zs));
    float m1 = fmaf(c01, xs, fmaf(c11, ys, c12 * zs));
    float m2 = fmaf(c02, xs, fmaf(c12, ys, c22 * zs));
    float g  = fmaf(m0, a_c, fmaf(m1, b_c, m2));   // sign of dot(n, xyz), d0>0
    float inv = rsqrtf(fmaf(m0, m0, fmaf(m1, m1, m2 * m2)));
    if (g > 0.0f) inv = -inv;
    if (!(d0 > 0.0f)) inv = 0.0f;                  // where(depth>0, n, 0)
    *nx = m0 * inv; *ny = m1 * inv; *nz = m2 * inv;
}

__global__ __launch_bounds__(256, 4)
void ppal_main(const float* __restrict__ pred, const float* __restrict__ gt,
               double* __restrict__ acc)
{
    const int tx = threadIdx.x;        // 0..15
    const int ty = threadIdx.y;        // 0..15
    const int tid = ty * 16 + tx;
    const int j0 = blockIdx.x * 32;
    const int i0 = blockIdx.y * 16;
    const int b  = blockIdx.z;

    const float invFX = 1.0f / 518.857f;
    const float invFY = 1.0f / 519.469f;

    // depth tile: rows i0-4..i0+18 (23), cols j0-4..j0+34 (39); stride 40
    __shared__ float sd[2][23 * 40];
    // column-sum records: entry t = i*39 + rc; {S1,Sb,Sbb,T1,Tb,pad} stride 6
    __shared__ float cs[2][624 * 6];

    const float* src0 = pred + (size_t)b * (HH * WW);
    const float* src1 = gt   + (size_t)b * (HH * WW);
    for (int idx = tid; idx < 23 * 40; idx += 256) {
        int lr = idx / 40, lc = idx - lr * 40;
        int r = i0 - 4 + lr, c = j0 - 4 + lc;
        bool ok = (lc < 39) && (r >= 0) && (r < HH) && (c >= 0) && (c < WW);
        int off = r * WW + c;
        sd[0][idx] = ok ? src0[off] : 0.0f;
        sd[1][idx] = ok ? src1[off] : 0.0f;
    }
    __syncthreads();

    // ---- stage 1: 624 row-reduction tasks; i = t/39, rc = t%39 ----
    for (int t = tid; t < 624; t += 256) {
        int i = t / 39;
        int c = t - i * 39;
        float S1[2] = {0.f, 0.f}, Sb[2] = {0.f, 0.f}, Sbb[2] = {0.f, 0.f};
        float T1[2] = {0.f, 0.f}, Tb[2] = {0.f, 0.f};
#pragma unroll
        for (int dr = 0; dr < 8; ++dr) {
            float bv = ((float)(i0 + i - 4 + dr) - 239.5f) * invFY;
#pragma unroll
            for (int k = 0; k < 2; ++k) {
                float d  = sd[k][(i + dr) * 40 + c];
                float bd = bv * d;
                T1[k] += d;
                Tb[k] += bd;
                S1[k]  = fmaf(d,  d,  S1[k]);
                Sb[k]  = fmaf(bd, d,  Sb[k]);
                Sbb[k] = fmaf(bd, bd, Sbb[k]);
            }
        }
#pragma unroll
        for (int k = 0; k < 2; ++k) {
            float* e = &cs[k][6 * t];
            *(float2*)(e)     = make_float2(S1[k], Sb[k]);
            *(float2*)(e + 2) = make_float2(Sbb[k], T1[k]);
            e[4] = Tb[k];
        }
    }
    __syncthreads();

    // ---- stage 2: 2 px/thread, shared-core combine + 4 f32 solves ----
    const int i  = i0 + ty;
    const int jl = j0 + 2 * tx;        // pixel p: j = jl + p
    const bool valid0 = (i < HH);                     // jl <= 638 always
    const bool valid1 = (i < HH) && (jl + 1 < WW);

    float aw[9], aw2[9];
#pragma unroll
    for (int m = 0; m < 9; ++m) {
        float a = ((float)(jl + m - 4) - 319.5f) * invFX;
        aw[m] = a;
        aw2[m] = a * a;
    }
    float bc = ((float)i - 239.5f) * invFY;
    const int ebase = ty * 39 + 2 * tx;   // record entry for m=0

    float n0A[3], n1A[3];   // input-0 normals for pixels 0,1
    float contrib = 0.0f;
#pragma unroll
    for (int k = 0; k < 2; ++k) {
        // shared core: m = 1..7 (used by both pixels)
        float Sxx = 0.f, Sxy = 0.f, Sxz = 0.f, Syy = 0.f, Syz = 0.f, Szz = 0.f;
        float Sxs = 0.f, Sys = 0.f, Szs = 0.f;
#pragma unroll
        for (int m = 1; m < 8; ++m) {
            const float* e = &cs[k][6 * (ebase + m)];
            float2 p01 = *(const float2*)(e);       // S1, Sb
            float2 p23 = *(const float2*)(e + 2);   // Sbb, T1
            float  tb  = e[4];                      // Tb
            Szz += p01.x;  Syz += p01.y;  Syy += p23.x;
            Szs += p23.y;  Sys += tb;
            Sxz = fmaf(aw[m],  p01.x, Sxz);
            Sxy = fmaf(aw[m],  p01.y, Sxy);
            Sxs = fmaf(aw[m],  p23.y, Sxs);
            Sxx = fmaf(aw2[m], p01.x, Sxx);
        }

        float nn[2][3];
#pragma unroll
        for (int p = 0; p < 2; ++p) {
            int m = (p == 0) ? 0 : 8;               // unique tap
            const float* e = &cs[k][6 * (ebase + m)];
            float2 p01 = *(const float2*)(e);
            float2 p23 = *(const float2*)(e + 2);
            float  tb  = e[4];
            float xx = fmaf(aw2[m], p01.x, Sxx);
            float xy = fmaf(aw[m],  p01.y, Sxy);
            float xz = fmaf(aw[m],  p01.x, Sxz);
            float yy = Syy + p23.x;
            float yz = Syz + p01.y;
            float zz = Szz + p01.x;
            float xs = fmaf(aw[m],  p23.y, Sxs);
            float ys = Sys + tb;
            float zs = Szs + p23.y;
            float d0 = sd[k][(ty + 4) * 40 + (2 * tx + p + 4)];
            solve_normal(xx, xy, xz, yy, yz, zz, xs, ys, zs,
                         aw[4 + p], bc, d0, &nn[p][0], &nn[p][1], &nn[p][2]);
        }
        if (k == 0) {
            n0A[0] = nn[0][0]; n0A[1] = nn[0][1]; n0A[2] = nn[0][2];
            n1A[0] = nn[1][0]; n1A[1] = nn[1][1]; n1A[2] = nn[1][2];
        } else {
            float c0 = fabsf(n0A[0] - nn[0][0]) + fabsf(n0A[1] - nn[0][1])
                     + fabsf(n0A[2] - nn[0][2]);
            float c1 = fabsf(n1A[0] - nn[1][0]) + fabsf(n1A[1] - nn[1][1])
                     + fabsf(n1A[2] - nn[1][2]);
            contrib = (valid0 ? c0 : 0.0f) + (valid1 ? c1 : 0.0f);
        }
    }

    // ---- reduce: wave shuffle -> LDS -> ONE plain STORE per block ----
    float v = contrib;
#pragma unroll
    for (int off = 32; off > 0; off >>= 1) v += __shfl_down(v, off, 64);
    __shared__ float wsum[4];
    int wid = tid >> 6, lane = tid & 63;
    if (lane == 0) wsum[wid] = v;
    __syncthreads();
    if (tid == 0) {
        double bs = (double)wsum[0] + (double)wsum[1] + (double)wsum[2] + (double)wsum[3];
        int slot = blockIdx.x + 20 * blockIdx.y + 600 * blockIdx.z;
        acc[slot] = bs;   // unique slot, written every launch -> no memset
    }
}

__global__ void ppal_finalize(const double* __restrict__ acc, float* __restrict__ out)
{
    int tid = threadIdx.x;             // 256 threads, one block
    double v = 0.0;
    for (int s = tid; s < NBLK; s += 256) v += acc[s];
#pragma unroll
    for (int off = 32; off > 0; off >>= 1) v += __shfl_down(v, off, 64);
    __shared__ double wsum[4];
    int wid = tid >> 6, lane = tid & 63;
    if (lane == 0) wsum[wid] = v;
    __syncthreads();
    if (tid == 0)
        out[0] = (float)((wsum[0] + wsum[1] + wsum[2] + wsum[3])
                         * (1.0 / 7345944.0));  // mean over B*3*H*W
}

extern "C" void kernel_launch(void* const* d_in, const int* in_sizes, int n_in,
                              void* d_out, int out_size, void* d_ws, size_t ws_size,
                              hipStream_t stream)
{
    const float* pred = (const float*)d_in[0];
    const float* gt   = (const float*)d_in[1];
    float* out  = (float*)d_out;
    double* acc = (double*)d_ws;

    dim3 grid(20, 30, BATCH);          // 32-col x 16-row tiles = 4800 blocks
    dim3 block(16, 16);
    ppal_main<<<grid, block, 0, stream>>>(pred, gt, acc);
    ppal_finalize<<<1, 256, 0, stream>>>(acc, out);
}

// Round 10
// 99.607 us; speedup vs baseline: 1.0453x; 1.0453x over previous
//
#include <hip/hip_runtime.h>

#define HH 479
#define WW 639
#define BATCH 8
#define NBLK (20 * 30 * 8)   // 4800 blocks

// Tile: 32 cols x 16 rows per block, 256 threads, 2 px/thread.
// Stage 1 (R10: sliding window): per (input k, row-half h, window-col c),
// maintain running 8-row sums {S1,Sb,Sbb,T1,Tb}; one init + 7 slide steps
// replaces 8 from-scratch 8-row sums (wall ~415 -> ~280 slots).
// Stage 2 (R8): adjacent pixels share 7/8 window columns with absolute
// weights {1,a_c,a_c^2} -> 9 shared core sums + 1 unique tap per pixel.
// Solve (f32, R5-validated): centered A_hat + Sherman-Morrison => same unit
// normal as (M+eps I)^-1 s; kills the ~1e8 raw-moment cofactor cancellation.
// Retirement: per-block STORE into acc[block_id] (no memset needed), tiny
// finalize kernel. (R2/R3: fence+counter readback poisons retirement.)

__device__ __forceinline__ void solve_normal(
    float xx, float xy, float xz, float yy, float yz, float zz,
    float xs, float ys, float zs,
    float a_c, float b_c, float d0,
    float* nx, float* ny, float* nz)
{
    const float EPSV = 1e-6f;
    const float inv64 = 1.0f / 64.0f;
    float hx = xs * inv64, hy = ys * inv64, hz = zs * inv64;
    float cxx = fmaf(-hx, xs, xx) + EPSV;
    float cxy = fmaf(-hx, ys, xy);
    float cxz = fmaf(-hx, zs, xz);
    float cyy = fmaf(-hy, ys, yy) + EPSV;
    float cyz = fmaf(-hy, zs, yz);
    float czz = fmaf(-hz, zs, zz) + EPSV;
    float c00 = fmaf(cyy, czz, -cyz * cyz);
    float c01 = fmaf(cxz, cyz, -cxy * czz);
    float c02 = fmaf(cxy, cyz, -cxz * cyy);
    float c11 = fmaf(cxx, czz, -cxz * cxz);
    float c12 = fmaf(cxy, cxz, -cxx * cyz);
    float c22 = fmaf(cxx, cyy, -cxy * cxy);
    float m0 = fmaf(c00, xs, fmaf(c01, ys, c02 * zs));
    float m1 = fmaf(c01, xs, fmaf(c11, ys, c12 * zs));
    float m2 = fmaf(c02, xs, fmaf(c12, ys, c22 * zs));
    float g  = fmaf(m0, a_c, fmaf(m1, b_c, m2));   // sign of dot(n, xyz), d0>0
    float inv = rsqrtf(fmaf(m0, m0, fmaf(m1, m1, m2 * m2)));
    if (g > 0.0f) inv = -inv;
    if (!(d0 > 0.0f)) inv = 0.0f;                  // where(depth>0, n, 0)
    *nx = m0 * inv; *ny = m1 * inv; *nz = m2 * inv;
}

__global__ __launch_bounds__(256, 4)
void ppal_main(const float* __restrict__ pred, const float* __restrict__ gt,
               double* __restrict__ acc)
{
    const int tx = threadIdx.x;        // 0..15
    const int ty = threadIdx.y;        // 0..15
    const int tid = ty * 16 + tx;
    const int j0 = blockIdx.x * 32;
    const int i0 = blockIdx.y * 16;
    const int b  = blockIdx.z;

    const float invFX = 1.0f / 518.857f;
    const float invFY = 1.0f / 519.469f;

    // depth tile: rows i0-4..i0+18 (23), cols j0-4..j0+34 (39); stride 40
    __shared__ float sd[2][23 * 40];
    // column-sum records: entry t = i*39 + rc; {S1,Sb,Sbb,T1,Tb,pad} stride 6
    __shared__ float cs[2][624 * 6];

    const float* src0 = pred + (size_t)b * (HH * WW);
    const float* src1 = gt   + (size_t)b * (HH * WW);
    for (int idx = tid; idx < 23 * 40; idx += 256) {
        int lr = idx / 40, lc = idx - lr * 40;
        int r = i0 - 4 + lr, c = j0 - 4 + lc;
        bool ok = (lc < 39) && (r >= 0) && (r < HH) && (c >= 0) && (c < WW);
        int off = r * WW + c;
        sd[0][idx] = ok ? src0[off] : 0.0f;
        sd[1][idx] = ok ? src1[off] : 0.0f;
    }
    __syncthreads();

    // ---- stage 1: sliding-window row reductions ----
    // task tid in [0,156): k = tid/78, h = (tid%78)/39, c = (tid%78)%39
    // output rows i = 8h..8h+7; window of output i = tile rows i..i+7
    if (tid < 156) {
        int k  = tid >= 78;
        int rm = tid - 78 * k;
        int h  = rm >= 39;
        int c  = rm - 39 * h;
        int rbase = 8 * h;
        float S1 = 0.f, Sb = 0.f, Sbb = 0.f, T1 = 0.f, Tb = 0.f;
#pragma unroll
        for (int r = 0; r < 8; ++r) {
            int rr = rbase + r;
            float d  = sd[k][rr * 40 + c];
            float bv = ((float)(i0 + rr - 4) - 239.5f) * invFY;
            float bd = bv * d;
            T1 += d;  Tb += bd;
            S1  = fmaf(d,  d,  S1);
            Sb  = fmaf(bd, d,  Sb);
            Sbb = fmaf(bd, bd, Sbb);
        }
        {
            float* e = &cs[k][6 * (rbase * 39 + c)];
            *(float2*)(e)     = make_float2(S1, Sb);
            *(float2*)(e + 2) = make_float2(Sbb, T1);
            e[4] = Tb;
        }
#pragma unroll
        for (int s = 1; s < 8; ++s) {
            int i = rbase + s;
            // window slides: tile row (i-1) leaves, tile row (i+7) enters
            float d0 = sd[k][(i - 1) * 40 + c];
            float d1 = sd[k][(i + 7) * 40 + c];
            float b0 = ((float)(i0 + i - 5)  - 239.5f) * invFY;
            float b1 = ((float)(i0 + i + 3)  - 239.5f) * invFY;
            float bd0 = b0 * d0, bd1 = b1 * d1;
            T1 += d1 - d0;
            Tb += bd1 - bd0;
            S1  += fmaf(d1,  d1,  -d0  * d0);
            Sb  += fmaf(bd1, d1,  -bd0 * d0);
            Sbb += fmaf(bd1, bd1, -bd0 * bd0);
            float* e = &cs[k][6 * (i * 39 + c)];
            *(float2*)(e)     = make_float2(S1, Sb);
            *(float2*)(e + 2) = make_float2(Sbb, T1);
            e[4] = Tb;
        }
    }
    __syncthreads();

    // ---- stage 2: 2 px/thread, shared-core combine + 4 f32 solves ----
    const int i  = i0 + ty;
    const int jl = j0 + 2 * tx;        // pixel p: j = jl + p
    const bool valid0 = (i < HH);                     // jl <= 638 always
    const bool valid1 = (i < HH) && (jl + 1 < WW);

    float aw[9], aw2[9];
#pragma unroll
    for (int m = 0; m < 9; ++m) {
        float a = ((float)(jl + m - 4) - 319.5f) * invFX;
        aw[m] = a;
        aw2[m] = a * a;
    }
    float bc = ((float)i - 239.5f) * invFY;
    const int ebase = ty * 39 + 2 * tx;   // record entry for m=0

    float n0A[3], n1A[3];   // input-0 normals for pixels 0,1
    float contrib = 0.0f;
#pragma unroll
    for (int k = 0; k < 2; ++k) {
        // shared core: m = 1..7 (used by both pixels)
        float Sxx = 0.f, Sxy = 0.f, Sxz = 0.f, Syy = 0.f, Syz = 0.f, Szz = 0.f;
        float Sxs = 0.f, Sys = 0.f, Szs = 0.f;
#pragma unroll
        for (int m = 1; m < 8; ++m) {
            const float* e = &cs[k][6 * (ebase + m)];
            float2 p01 = *(const float2*)(e);       // S1, Sb
            float2 p23 = *(const float2*)(e + 2);   // Sbb, T1
            float  tb  = e[4];                      // Tb
            Szz += p01.x;  Syz += p01.y;  Syy += p23.x;
            Szs += p23.y;  Sys += tb;
            Sxz = fmaf(aw[m],  p01.x, Sxz);
            Sxy = fmaf(aw[m],  p01.y, Sxy);
            Sxs = fmaf(aw[m],  p23.y, Sxs);
            Sxx = fmaf(aw2[m], p01.x, Sxx);
        }

        float nn[2][3];
#pragma unroll
        for (int p = 0; p < 2; ++p) {
            int m = (p == 0) ? 0 : 8;               // unique tap
            const float* e = &cs[k][6 * (ebase + m)];
            float2 p01 = *(const float2*)(e);
            float2 p23 = *(const float2*)(e + 2);
            float  tb  = e[4];
            float xx = fmaf(aw2[m], p01.x, Sxx);
            float xy = fmaf(aw[m],  p01.y, Sxy);
            float xz = fmaf(aw[m],  p01.x, Sxz);
            float yy = Syy + p23.x;
            float yz = Syz + p01.y;
            float zz = Szz + p01.x;
            float xs = fmaf(aw[m],  p23.y, Sxs);
            float ys = Sys + tb;
            float zs = Szs + p23.y;
            float d0 = sd[k][(ty + 4) * 40 + (2 * tx + p + 4)];
            solve_normal(xx, xy, xz, yy, yz, zz, xs, ys, zs,
                         aw[4 + p], bc, d0, &nn[p][0], &nn[p][1], &nn[p][2]);
        }
        if (k == 0) {
            n0A[0] = nn[0][0]; n0A[1] = nn[0][1]; n0A[2] = nn[0][2];
            n1A[0] = nn[1][0]; n1A[1] = nn[1][1]; n1A[2] = nn[1][2];
        } else {
            float c0 = fabsf(n0A[0] - nn[0][0]) + fabsf(n0A[1] - nn[0][1])
                     + fabsf(n0A[2] - nn[0][2]);
            float c1 = fabsf(n1A[0] - nn[1][0]) + fabsf(n1A[1] - nn[1][1])
                     + fabsf(n1A[2] - nn[1][2]);
            contrib = (valid0 ? c0 : 0.0f) + (valid1 ? c1 : 0.0f);
        }
    }

    // ---- reduce: wave shuffle -> LDS -> ONE plain STORE per block ----
    float v = contrib;
#pragma unroll
    for (int off = 32; off > 0; off >>= 1) v += __shfl_down(v, off, 64);
    __shared__ float wsum[4];
    int wid = tid >> 6, lane = tid & 63;
    if (lane == 0) wsum[wid] = v;
    __syncthreads();
    if (tid == 0) {
        double bs = (double)wsum[0] + (double)wsum[1] + (double)wsum[2] + (double)wsum[3];
        int slot = blockIdx.x + 20 * blockIdx.y + 600 * blockIdx.z;
        acc[slot] = bs;   // unique slot, written every launch -> no memset
    }
}

__global__ void ppal_finalize(const double* __restrict__ acc, float* __restrict__ out)
{
    int tid = threadIdx.x;             // 256 threads, one block
    double v = 0.0;
    for (int s = tid; s < NBLK; s += 256) v += acc[s];
#pragma unroll
    for (int off = 32; off > 0; off >>= 1) v += __shfl_down(v, off, 64);
    __shared__ double wsum[4];
    int wid = tid >> 6, lane = tid & 63;
    if (lane == 0) wsum[wid] = v;
    __syncthreads();
    if (tid == 0)
        out[0] = (float)((wsum[0] + wsum[1] + wsum[2] + wsum[3])
                         * (1.0 / 7345944.0));  // mean over B*3*H*W
}

extern "C" void kernel_launch(void* const* d_in, const int* in_sizes, int n_in,
                              void* d_out, int out_size, void* d_ws, size_t ws_size,
                              hipStream_t stream)
{
    const float* pred = (const float*)d_in[0];
    const float* gt   = (const float*)d_in[1];
    float* out  = (float*)d_out;
    double* acc = (double*)d_ws;

    dim3 grid(20, 30, BATCH);          // 32-col x 16-row tiles = 4800 blocks
    dim3 block(16, 16);
    ppal_main<<<grid, block, 0, stream>>>(pred, gt, acc);
    ppal_finalize<<<1, 256, 0, stream>>>(acc, out);
}